// Round 1
// baseline (474.579 us; speedup 1.0000x reference)
//
#include <hip/hip_runtime.h>
#include <math.h>

// ---------------------------------------------------------------------------
// QMixer forward, fused. 32768 tokens, per token:
//   ent(16x64) -> energy(16x16, softmax over query axis) -> attn_out(64)
//   -> hypernet (w1/b1/wf/v) -> q_tot scalar.
// Algebraic fusions (precomputed into d_ws by setup_fused):
//   Wqk  = q_w @ k_w^T            (64x64)   energy[i,j] = ent_i Wqk ent_j + ent_i . u
//   u    = q_w @ k_b              (64)      (j-only terms cancel in softmax over i)
//   Wh1c = tre_w @ hw1_w1[128:192](64x64)   tre never materialized
//   Whfc = tre_w @ hwf_w1[64:128] (64x64)
//   Wb1c = tre_w @ hb1_w[64:128]  (64x32)
//   Wvc  = tre_w @ v_w1[64:128]   (64x32)
//   bh1/bhf/bb1/bv = bias + tre_b @ (same slices)
// ---------------------------------------------------------------------------

#define TOKS 32768

// ws float offsets
#define WS_WQK   0
#define WS_WH1C  4096
#define WS_WHFC  8192
#define WS_WB1C  12288
#define WS_WVC   14336
#define WS_U     16384
#define WS_BH1   16448
#define WS_BHF   16512
#define WS_BB1   16576
#define WS_BV    16608
#define WS_TOTAL 16640

__global__ __launch_bounds__(256) void setup_fused(
    const float* __restrict__ qw, const float* __restrict__ kw, const float* __restrict__ kb,
    const float* __restrict__ trew, const float* __restrict__ treb,
    const float* __restrict__ hw1w1, const float* __restrict__ hw1b1,
    const float* __restrict__ hwfw1, const float* __restrict__ hwfb1,
    const float* __restrict__ hb1w, const float* __restrict__ hb1b,
    const float* __restrict__ vw1, const float* __restrict__ vb1,
    float* __restrict__ ws)
{
    int gid = blockIdx.x * 256 + threadIdx.x;
    if (gid >= WS_TOTAL) return;
    float s = 0.f;
    if (gid < WS_WH1C) {                       // Wqk[a][b] = sum_g q_w[a,g]*k_w[b,g]
        int a = gid >> 6, b = gid & 63;
        for (int g = 0; g < 64; ++g) s += qw[a*64+g] * kw[b*64+g];
    } else if (gid < WS_WHFC) {                // Wh1c
        int i = gid - WS_WH1C; int f = i >> 6, e = i & 63;
        for (int g = 0; g < 64; ++g) s += trew[f*64+g] * hw1w1[(128+g)*64+e];
    } else if (gid < WS_WB1C) {                // Whfc
        int i = gid - WS_WHFC; int f = i >> 6, e = i & 63;
        for (int g = 0; g < 64; ++g) s += trew[f*64+g] * hwfw1[(64+g)*64+e];
    } else if (gid < WS_WVC) {                 // Wb1c
        int i = gid - WS_WB1C; int f = i >> 5, m = i & 31;
        for (int g = 0; g < 64; ++g) s += trew[f*64+g] * hb1w[(64+g)*32+m];
    } else if (gid < WS_U) {                   // Wvc
        int i = gid - WS_WVC; int f = i >> 5, m = i & 31;
        for (int g = 0; g < 64; ++g) s += trew[f*64+g] * vw1[(64+g)*32+m];
    } else if (gid < WS_BH1) {                 // u[f] = sum_g q_w[f,g]*k_b[g]
        int f = gid - WS_U;
        for (int g = 0; g < 64; ++g) s += qw[f*64+g] * kb[g];
    } else if (gid < WS_BHF) {
        int e = gid - WS_BH1; s = hw1b1[e];
        for (int g = 0; g < 64; ++g) s += treb[g] * hw1w1[(128+g)*64+e];
    } else if (gid < WS_BB1) {
        int e = gid - WS_BHF; s = hwfb1[e];
        for (int g = 0; g < 64; ++g) s += treb[g] * hwfw1[(64+g)*64+e];
    } else if (gid < WS_BV) {
        int m = gid - WS_BB1; s = hb1b[m];
        for (int g = 0; g < 64; ++g) s += treb[g] * hb1w[(64+g)*32+m];
    } else {
        int m = gid - WS_BV; s = vb1[m];
        for (int g = 0; g < 64; ++g) s += treb[g] * vw1[(64+g)*32+m];
    }
    ws[gid] = s;
}

// per-wave LDS slab (floats): IN 1024 | MU 512 | ENT 16x68 | TMP 16x68 (H1 8x64
// overlays TMP once dead) | AO 64 | MM 64 | Z 64 | RS 16
#define SLAB 3920

__global__ __launch_bounds__(128) void qmix_main(
    const float* __restrict__ agent_qs, const float* __restrict__ states,
    const float* __restrict__ mu,
    const float* __restrict__ ally_w, const float* __restrict__ ally_b,
    const float* __restrict__ enemy_w, const float* __restrict__ enemy_b,
    const float* __restrict__ hw1_w1, const float* __restrict__ hw1_w2,
    const float* __restrict__ hw1_b2,
    const float* __restrict__ hwf_w1, const float* __restrict__ hwf_w2,
    const float* __restrict__ hwf_b2,
    const float* __restrict__ hb1_w, const float* __restrict__ v_w1,
    const float* __restrict__ v_w2, const float* __restrict__ v_b2,
    const float* __restrict__ ws,
    float* __restrict__ out)
{
    __shared__ float smem[2 * SLAB];
    const int e    = threadIdx.x & 63;
    const int wv   = threadIdx.x >> 6;
    const int t    = blockIdx.x * 2 + wv;

    float* sIN  = smem + wv * SLAB;   // [16][64] states rows (ally 0..7, enemy 8..15)
    float* sMU  = sIN + 1024;         // [8][64]
    float* sENT = sMU + 512;          // [16][68]
    float* sTMP = sENT + 1088;        // [16][68]
    float* sH1  = sTMP;               // [8][64] overlay (TMP dead by then)
    float* sAO  = sTMP + 1088;        // [64]
    float* sMM  = sAO + 64;           // [64]
    float* sZ   = sMM + 64;           // [64]
    float* sRS  = sZ + 64;            // [16]

    const float* Wqk  = ws + WS_WQK;
    const float* Wh1c = ws + WS_WH1C;
    const float* Whfc = ws + WS_WHFC;
    const float* Wb1c = ws + WS_WB1C;
    const float* Wvc  = ws + WS_WVC;
    const float* uvec = ws + WS_U;
    const float* bh1  = ws + WS_BH1;
    const float* bhf  = ws + WS_BHF;
    const float* bb1  = ws + WS_BB1;
    const float* bv   = ws + WS_BV;

    // ---- Phase A: stage inputs -------------------------------------------
    const float* st  = states + (size_t)t * 1024;
    const float* mup = mu + (size_t)t * 512;
    #pragma unroll
    for (int n = 0; n < 16; ++n) sIN[n*64 + e] = st[n*64 + e];
    float mm = 0.f;
    #pragma unroll
    for (int n = 0; n < 8; ++n) { float v = mup[n*64 + e]; sMU[n*64 + e] = v; mm += v; }
    sMM[e] = mm * 0.125f;
    __syncthreads();

    // ---- Phase B: ent = [ally;enemy] @ {ally_w,enemy_w} + bias ------------
    float acc[16];
    {
        float ba = ally_b[e], be = enemy_b[e];
        #pragma unroll
        for (int n = 0; n < 8;  ++n) acc[n] = ba;
        #pragma unroll
        for (int n = 8; n < 16; ++n) acc[n] = be;
    }
    for (int f4 = 0; f4 < 64; f4 += 4) {
        float wa[4], we[4];
        #pragma unroll
        for (int q = 0; q < 4; ++q) {
            wa[q] = ally_w[(f4+q)*64 + e];
            we[q] = enemy_w[(f4+q)*64 + e];
        }
        #pragma unroll
        for (int n = 0; n < 8; ++n) {
            float4 iv = *reinterpret_cast<const float4*>(&sIN[n*64 + f4]);
            acc[n] += iv.x*wa[0] + iv.y*wa[1] + iv.z*wa[2] + iv.w*wa[3];
        }
        #pragma unroll
        for (int n = 8; n < 16; ++n) {
            float4 iv = *reinterpret_cast<const float4*>(&sIN[n*64 + f4]);
            acc[n] += iv.x*we[0] + iv.y*we[1] + iv.z*we[2] + iv.w*we[3];
        }
    }
    #pragma unroll
    for (int n = 0; n < 16; ++n) sENT[n*68 + e] = acc[n];
    __syncthreads();

    // ---- Phase C: tmp = ent @ Wqk ------------------------------------------
    float acc2[16];
    #pragma unroll
    for (int n = 0; n < 16; ++n) acc2[n] = 0.f;
    for (int f4 = 0; f4 < 64; f4 += 4) {
        float wq[4];
        #pragma unroll
        for (int q = 0; q < 4; ++q) wq[q] = Wqk[(f4+q)*64 + e];
        #pragma unroll
        for (int n = 0; n < 16; ++n) {
            float4 ev = *reinterpret_cast<const float4*>(&sENT[n*68 + f4]);
            acc2[n] += ev.x*wq[0] + ev.y*wq[1] + ev.z*wq[2] + ev.w*wq[3];
        }
    }
    #pragma unroll
    for (int n = 0; n < 16; ++n) sTMP[n*68 + e] = acc2[n];
    __syncthreads();

    // ---- Phase D: energy[i][j] = tmp_i . ent_j + ent_i . u; softmax over i --
    const int ii = e & 15, jg = e >> 4;   // lane covers (i=ii, j=jg*4+jj)
    float en0 = 0.f, en1 = 0.f, en2 = 0.f, en3 = 0.f, si = 0.f;
    for (int f4 = 0; f4 < 64; f4 += 4) {
        float4 uv = *reinterpret_cast<const float4*>(&uvec[f4]);
        float4 tv = *reinterpret_cast<const float4*>(&sTMP[ii*68 + f4]);
        float4 iv = *reinterpret_cast<const float4*>(&sENT[ii*68 + f4]);
        float4 e0 = *reinterpret_cast<const float4*>(&sENT[(jg*4+0)*68 + f4]);
        float4 e1 = *reinterpret_cast<const float4*>(&sENT[(jg*4+1)*68 + f4]);
        float4 e2 = *reinterpret_cast<const float4*>(&sENT[(jg*4+2)*68 + f4]);
        float4 e3 = *reinterpret_cast<const float4*>(&sENT[(jg*4+3)*68 + f4]);
        si  += iv.x*uv.x + iv.y*uv.y + iv.z*uv.z + iv.w*uv.w;
        en0 += tv.x*e0.x + tv.y*e0.y + tv.z*e0.z + tv.w*e0.w;
        en1 += tv.x*e1.x + tv.y*e1.y + tv.z*e1.z + tv.w*e1.w;
        en2 += tv.x*e2.x + tv.y*e2.y + tv.z*e2.z + tv.w*e2.w;
        en3 += tv.x*e3.x + tv.y*e3.y + tv.z*e3.z + tv.w*e3.w;
    }
    float enj[4] = { en0 + si, en1 + si, en2 + si, en3 + si };
    // softmax over i: the 16 i-values for a column live in one 16-lane group
    #pragma unroll
    for (int jj = 0; jj < 4; ++jj) {
        float m = enj[jj];
        m = fmaxf(m, __shfl_xor(m, 1, 16));
        m = fmaxf(m, __shfl_xor(m, 2, 16));
        m = fmaxf(m, __shfl_xor(m, 4, 16));
        m = fmaxf(m, __shfl_xor(m, 8, 16));
        float p = expf(enj[jj] - m);
        float ssum = p;
        ssum += __shfl_xor(ssum, 1, 16);
        ssum += __shfl_xor(ssum, 2, 16);
        ssum += __shfl_xor(ssum, 4, 16);
        ssum += __shfl_xor(ssum, 8, 16);
        enj[jj] = p / ssum;
    }
    // rowsum over k (across the 4 jg groups)
    float rs = enj[0] + enj[1] + enj[2] + enj[3];
    rs += __shfl_xor(rs, 16);
    rs += __shfl_xor(rs, 32);
    if (e < 16) sRS[e] = rs;
    __syncthreads();
    // attn_out[e] = (1/16) sum_n rowsum[n] * ent[n][e]
    float ao = 0.f;
    #pragma unroll
    for (int n = 0; n < 16; ++n) ao += sRS[n] * sENT[n*68 + e];
    sAO[e] = ao * (1.f / 16.f);
    __syncthreads();

    // ---- Phase E: token-level GEMVs + per-agent hypernet -------------------
    const int m_ = e & 31;
    float hsh = bh1[e], z = bhf[e], b1v = bb1[m_], rv = bv[m_];
    for (int f = 0; f < 64; ++f) {
        float aof = sAO[f], mmf = sMM[f];
        hsh += aof * hw1_w1[f*64 + e];
        z   += aof * hwf_w1[f*64 + e] + mmf * Whfc[f*64 + e];
        b1v += aof * hb1_w[f*32 + m_] + mmf * Wb1c[f*32 + m_];
        rv  += aof * v_w1[f*32 + m_]  + mmf * Wvc[f*32 + m_];
    }
    z  = fmaxf(z, 0.f);
    rv = fmaxf(rv, 0.f);
    sZ[e] = z;

    float h1a[8];
    #pragma unroll
    for (int a = 0; a < 8; ++a) h1a[a] = hsh;
    for (int f4 = 0; f4 < 64; f4 += 4) {
        float wb[4], wc[4];
        #pragma unroll
        for (int q = 0; q < 4; ++q) {
            wb[q] = hw1_w1[(64 + f4 + q)*64 + e];
            wc[q] = Wh1c[(f4 + q)*64 + e];
        }
        #pragma unroll
        for (int a = 0; a < 8; ++a) {
            float4 iv = *reinterpret_cast<const float4*>(&sIN[a*64 + f4]);
            float4 mv = *reinterpret_cast<const float4*>(&sMU[a*64 + f4]);
            h1a[a] += iv.x*wb[0] + iv.y*wb[1] + iv.z*wb[2] + iv.w*wb[3]
                    + mv.x*wc[0] + mv.y*wc[1] + mv.z*wc[2] + mv.w*wc[3];
        }
    }
    #pragma unroll
    for (int a = 0; a < 8; ++a) sH1[a*64 + e] = fmaxf(h1a[a], 0.f);
    __syncthreads();

    // ---- w1, hidden, wf, v, q_tot ------------------------------------------
    const int ag0 = e >> 5;      // lanes 0..31: even agents; 32..63: odd agents
    float w1v0 = hw1_b2[m_], w1v1 = w1v0, w1v2 = w1v0, w1v3 = w1v0;
    for (int g = 0; g < 64; ++g) {
        float w2 = hw1_w2[g*32 + m_];
        w1v0 += sH1[(ag0+0)*64 + g] * w2;
        w1v1 += sH1[(ag0+2)*64 + g] * w2;
        w1v2 += sH1[(ag0+4)*64 + g] * w2;
        w1v3 += sH1[(ag0+6)*64 + g] * w2;
    }
    const float* qs = agent_qs + (size_t)t * 8;
    float hid = qs[ag0+0]*fabsf(w1v0) + qs[ag0+2]*fabsf(w1v1)
              + qs[ag0+4]*fabsf(w1v2) + qs[ag0+6]*fabsf(w1v3);
    hid += __shfl_xor(hid, 32);
    hid += b1v;
    hid = (hid > 0.f) ? hid : (expf(hid) - 1.f);   // elu

    float wf = hwf_b2[m_];
    for (int g = 0; g < 64; ++g) wf += sZ[g] * hwf_w2[g*32 + m_];
    wf = fabsf(wf);

    float part = hid * wf + rv * v_w2[m_];
    part += __shfl_xor(part, 1, 32);
    part += __shfl_xor(part, 2, 32);
    part += __shfl_xor(part, 4, 32);
    part += __shfl_xor(part, 8, 32);
    part += __shfl_xor(part, 16, 32);
    if (e == 0) out[t] = part + v_b2[0];
}

extern "C" void kernel_launch(void* const* d_in, const int* in_sizes, int n_in,
                              void* d_out, int out_size, void* d_ws, size_t ws_size,
                              hipStream_t stream)
{
    const float* agent_qs = (const float*)d_in[0];
    const float* states   = (const float*)d_in[1];
    const float* mu       = (const float*)d_in[2];
    const float* ally_w   = (const float*)d_in[3];
    const float* ally_b   = (const float*)d_in[4];
    const float* enemy_w  = (const float*)d_in[5];
    const float* enemy_b  = (const float*)d_in[6];
    const float* q_w      = (const float*)d_in[7];
    // d_in[8] = q_b: cancels in softmax over query axis, unused
    const float* k_w      = (const float*)d_in[9];
    const float* k_b      = (const float*)d_in[10];
    const float* hw1_w1   = (const float*)d_in[11];
    const float* hw1_b1   = (const float*)d_in[12];
    const float* hw1_w2   = (const float*)d_in[13];
    const float* hw1_b2   = (const float*)d_in[14];
    const float* hwf_w1   = (const float*)d_in[15];
    const float* hwf_b1   = (const float*)d_in[16];
    const float* hwf_w2   = (const float*)d_in[17];
    const float* hwf_b2   = (const float*)d_in[18];
    const float* hb1_w    = (const float*)d_in[19];
    const float* hb1_b    = (const float*)d_in[20];
    const float* v_w1     = (const float*)d_in[21];
    const float* v_b1     = (const float*)d_in[22];
    const float* v_w2     = (const float*)d_in[23];
    const float* v_b2     = (const float*)d_in[24];
    const float* tre_w    = (const float*)d_in[25];
    const float* tre_b    = (const float*)d_in[26];

    float* ws  = (float*)d_ws;
    float* out = (float*)d_out;

    hipLaunchKernelGGL(setup_fused, dim3(65), dim3(256), 0, stream,
                       q_w, k_w, k_b, tre_w, tre_b,
                       hw1_w1, hw1_b1, hwf_w1, hwf_b1,
                       hb1_w, hb1_b, v_w1, v_b1, ws);

    hipLaunchKernelGGL(qmix_main, dim3(TOKS / 2), dim3(128), 0, stream,
                       agent_qs, states, mu,
                       ally_w, ally_b, enemy_w, enemy_b,
                       hw1_w1, hw1_w2, hw1_b2,
                       hwf_w1, hwf_w2, hwf_b2,
                       hb1_w, v_w1, v_w2, v_b2,
                       ws, out);
}

// Round 2
// 215.004 us; speedup vs baseline: 2.2073x; 2.2073x over previous
//
#include <hip/hip_runtime.h>
#include <math.h>

// ---------------------------------------------------------------------------
// QMixer forward, MFMA version.
// Per token: ent(16x64) -> tmp = ent@Wqk' -> energy = tmp@ent^T (softmax over
// query axis, folded-u rank-1 term) -> attn_out -> hypernet -> q_tot.
// All matmuls on v_mfma_f32_16x16x32_bf16 (A/B bf16, fp32 accum).
//
// d_ws layout (setup kernel writes; [N][K] "B^T" layouts, bf16):
//   CAT  [64][128]  ent weights:  k<64 ally_w^T, k>=64 enemy_w^T
//   WQKT [80][64]   n<64: Wqk^T (Wqk = q_w @ k_w^T); n==64: u = q_w @ k_b; 65..79: 0
//   ZBRT [128][128] n<64: z (hwf_w1 | tre_w@hwf_w1[64:]); n<96: b1; n<128: rv
//   H1T  [64][192]  k<64: hw1_w1[64:128] (ally); k<128: tre_w@hw1_w1[128:192] (mu);
//                   k<192: hw1_w1[0:64] (attn_out)
//   W2T  [32][64]   hw1_w2^T
//   WFT  [32][64]   hwf_w2^T
//   biases fp32: BH1[64] BHF[64] BB1[32] BV[32]  (tre_b contributions folded)
// ---------------------------------------------------------------------------

#define TOKS 32768

typedef __attribute__((ext_vector_type(8))) short short8;
typedef __attribute__((ext_vector_type(4))) float f32x4;

#define MFMA(a, b, c) __builtin_amdgcn_mfma_f32_16x16x32_bf16((a), (b), (c), 0, 0, 0)

// ws element offsets (ushort units for bf16 part)
#define E_CAT   0
#define E_WQKT  8192
#define E_ZBRT  13312
#define E_H1T   29696
#define E_W2T   41984
#define E_WFT   44032
#define E_BF16_TOTAL 46080          // floats start at byte 92160

__device__ __forceinline__ unsigned short bfr(float x) {
    unsigned u = __builtin_bit_cast(unsigned, x);
    u += 0x7fffu + ((u >> 16) & 1u);           // round-to-nearest-even
    return (unsigned short)(u >> 16);
}
__device__ __forceinline__ float bf2f(unsigned short h) {
    unsigned u = ((unsigned)h) << 16;
    return __builtin_bit_cast(float, u);
}
__device__ __forceinline__ short8 cvt8(const float* __restrict__ p) {
    float4 a = *(const float4*)p;
    float4 b = *(const float4*)(p + 4);
    short8 r;
    r[0] = (short)bfr(a.x); r[1] = (short)bfr(a.y);
    r[2] = (short)bfr(a.z); r[3] = (short)bfr(a.w);
    r[4] = (short)bfr(b.x); r[5] = (short)bfr(b.y);
    r[6] = (short)bfr(b.z); r[7] = (short)bfr(b.w);
    return r;
}
// XOR swizzle (element units, 8-elem = 16B granules): kills the stride-128B
// row conflict on ds_read_b128 (guide §6 G4).
__device__ __forceinline__ int swz(int row, int col, int W) {
    return (row * W + col) ^ ((row & 7) << 3);
}

// ---------------------------------------------------------------------------
__global__ __launch_bounds__(256) void qmix_setup(
    const float* __restrict__ ally_w, const float* __restrict__ enemy_w,
    const float* __restrict__ q_w, const float* __restrict__ k_w,
    const float* __restrict__ k_b,
    const float* __restrict__ hw1_w1, const float* __restrict__ hw1_b1,
    const float* __restrict__ hw1_w2,
    const float* __restrict__ hwf_w1, const float* __restrict__ hwf_b1,
    const float* __restrict__ hwf_w2,
    const float* __restrict__ hb1_w, const float* __restrict__ hb1_b,
    const float* __restrict__ v_w1, const float* __restrict__ v_b1,
    const float* __restrict__ tre_w, const float* __restrict__ tre_b,
    unsigned short* __restrict__ wsb, float* __restrict__ wsf)
{
    int gid = blockIdx.x * 256 + threadIdx.x;
    if (gid < E_BF16_TOTAL) {
        float v = 0.f;
        if (gid < E_WQKT) {                         // CAT [64][128]
            int n = gid >> 7, k = gid & 127;
            v = (k < 64) ? ally_w[k * 64 + n] : enemy_w[(k - 64) * 64 + n];
        } else if (gid < E_ZBRT) {                  // WQKT [80][64]
            int i = gid - E_WQKT; int n = i >> 6, k = i & 63;
            if (n < 64) {
                for (int g = 0; g < 64; ++g) v += q_w[k * 64 + g] * k_w[n * 64 + g];
            } else if (n == 64) {
                for (int g = 0; g < 64; ++g) v += q_w[k * 64 + g] * k_b[g];
            }
        } else if (gid < E_H1T) {                   // ZBRT [128][128]
            int i = gid - E_ZBRT; int n = i >> 7, k = i & 127;
            if (n < 64) {
                if (k < 64) v = hwf_w1[k * 64 + n];
                else for (int g = 0; g < 64; ++g) v += tre_w[(k - 64) * 64 + g] * hwf_w1[(64 + g) * 64 + n];
            } else if (n < 96) {
                int m = n - 64;
                if (k < 64) v = hb1_w[k * 32 + m];
                else for (int g = 0; g < 64; ++g) v += tre_w[(k - 64) * 64 + g] * hb1_w[(64 + g) * 32 + m];
            } else {
                int m = n - 96;
                if (k < 64) v = v_w1[k * 32 + m];
                else for (int g = 0; g < 64; ++g) v += tre_w[(k - 64) * 64 + g] * v_w1[(64 + g) * 32 + m];
            }
        } else if (gid < E_W2T) {                   // H1T [64][192]
            int i = gid - E_H1T; int n = i / 192, k = i % 192;
            if (k < 64) v = hw1_w1[(64 + k) * 64 + n];
            else if (k < 128) {
                for (int g = 0; g < 64; ++g) v += tre_w[(k - 64) * 64 + g] * hw1_w1[(128 + g) * 64 + n];
            } else v = hw1_w1[(k - 128) * 64 + n];
        } else if (gid < E_WFT) {                   // W2T [32][64]
            int i = gid - E_W2T; int n = i >> 6, k = i & 63;
            v = hw1_w2[k * 32 + n];
        } else {                                    // WFT [32][64]
            int i = gid - E_WFT; int n = i >> 6, k = i & 63;
            v = hwf_w2[k * 32 + n];
        }
        wsb[gid] = bfr(v);
    } else if (gid < E_BF16_TOTAL + 192) {
        int j = gid - E_BF16_TOTAL; float v;
        if (j < 64) {
            v = hw1_b1[j];
            for (int g = 0; g < 64; ++g) v += tre_b[g] * hw1_w1[(128 + g) * 64 + j];
        } else if (j < 128) {
            int e = j - 64; v = hwf_b1[e];
            for (int g = 0; g < 64; ++g) v += tre_b[g] * hwf_w1[(64 + g) * 64 + e];
        } else if (j < 160) {
            int m = j - 128; v = hb1_b[m];
            for (int g = 0; g < 64; ++g) v += tre_b[g] * hb1_w[(64 + g) * 32 + m];
        } else {
            int m = j - 160; v = v_b1[m];
            for (int g = 0; g < 64; ++g) v += tre_b[g] * v_w1[(64 + g) * 32 + m];
        }
        wsf[j] = v;
    }
}

// ---------------------------------------------------------------------------
// Block = 4 waves = 16 tokens (4 per wave).
__global__ __launch_bounds__(256) void qmix_mfma(
    const float* __restrict__ agent_qs, const float* __restrict__ states,
    const float* __restrict__ mu,
    const float* __restrict__ ally_b, const float* __restrict__ enemy_b,
    const float* __restrict__ v_w2, const float* __restrict__ v_b2,
    const float* __restrict__ hw1_b2, const float* __restrict__ hwf_b2,
    const unsigned short* __restrict__ wsb, const float* __restrict__ wsf,
    float* __restrict__ out)
{
    __shared__ unsigned short sENT[4][16 * 96];   // per wave: ent [16][96] (col64=1, 65..95=0)
    __shared__ unsigned short sTMP[4][16 * 96];   // per wave: tmp [16][96]; reused as h1 [16][64]
    __shared__ unsigned short sAO[16 * 64];       // attn_out, block tokens, bf16
    __shared__ unsigned short sMM[16 * 64];       // mean-mu, block tokens, bf16
    __shared__ unsigned short sZ [16 * 64];       // relu(z), block tokens, bf16
    __shared__ float sB1[16 * 32];
    __shared__ float sWF[16 * 32];
    __shared__ float sV [16];
    __shared__ float sRS[4][16];

    const int lane = threadIdx.x & 63;
    const int wv   = threadIdx.x >> 6;
    const int l15  = lane & 15;
    const int lg   = lane >> 4;
    const int kb   = lg * 8;
    const int tok0 = blockIdx.x * 16;

    const unsigned short* CAT  = wsb + E_CAT;
    const unsigned short* WQKT = wsb + E_WQKT;
    const unsigned short* ZBRT = wsb + E_ZBRT;
    const unsigned short* H1T  = wsb + E_H1T;
    const unsigned short* W2T  = wsb + E_W2T;
    const unsigned short* WFT  = wsb + E_WFT;
    const float* BH1 = wsf + 0;
    const float* BHF = wsf + 64;
    const float* BB1 = wsf + 128;
    const float* BV  = wsf + 160;

    const short8 zero8 = {0, 0, 0, 0, 0, 0, 0, 0};
    const f32x4  zero4 = {0.f, 0.f, 0.f, 0.f};

    // init pad columns 64..95 (wave-private, no barrier needed)
    for (int i = lane; i < 16 * 32; i += 64) {
        int r = i >> 5, c = 64 + (i & 31);
        sENT[wv][swz(r, c, 96)] = (c == 64) ? (unsigned short)0x3F80 : (unsigned short)0;
        sTMP[wv][swz(r, c, 96)] = 0;
    }

    // ================= phase 1: per-token B, C, D =================
    for (int ti = 0; ti < 4; ++ti) {
        const int tl = wv * 4 + ti;
        const size_t t = (size_t)(tok0 + tl);

        // ---- B: ent = [ally;enemy] @ CAT  (M=16, N=64, K=128 block-diag) ----
        f32x4 accB[4] = {zero4, zero4, zero4, zero4};
        #pragma unroll
        for (int ks = 0; ks < 4; ++ks) {
            short8 af;
            if (ks < 2) {
                af = (l15 < 8) ? cvt8(states + t * 1024 + l15 * 64 + ks * 32 + kb) : zero8;
            } else {
                af = (l15 >= 8) ? cvt8(states + t * 1024 + 512 + (l15 - 8) * 64 + (ks - 2) * 32 + kb) : zero8;
            }
            #pragma unroll
            for (int nt = 0; nt < 4; ++nt) {
                short8 bfv = *(const short8*)&CAT[(nt * 16 + l15) * 128 + ks * 32 + kb];
                accB[nt] = MFMA(af, bfv, accB[nt]);
            }
        }
        #pragma unroll
        for (int nt = 0; nt < 4; ++nt) {
            int col = nt * 16 + l15;
            float ab = ally_b[col], eb = enemy_b[col];
            #pragma unroll
            for (int reg = 0; reg < 4; ++reg) {
                int r = lg * 4 + reg;
                sENT[wv][swz(r, col, 96)] = bfr(accB[nt][reg] + (r < 8 ? ab : eb));
            }
        }

        // ---- C: tmp = ent @ WQKT  (N=80; col 64 = si = ent.u) ----
        f32x4 accC[5] = {zero4, zero4, zero4, zero4, zero4};
        #pragma unroll
        for (int ks = 0; ks < 2; ++ks) {
            short8 af = *(const short8*)&sENT[wv][swz(l15, ks * 32 + kb, 96)];
            #pragma unroll
            for (int nt = 0; nt < 5; ++nt) {
                short8 bfv = *(const short8*)&WQKT[(nt * 16 + l15) * 64 + ks * 32 + kb];
                accC[nt] = MFMA(af, bfv, accC[nt]);
            }
        }
        #pragma unroll
        for (int nt = 0; nt < 5; ++nt) {
            #pragma unroll
            for (int reg = 0; reg < 4; ++reg)
                sTMP[wv][swz(lg * 4 + reg, nt * 16 + l15, 96)] = bfr(accC[nt][reg]);
        }

        // ---- D: energy = tmp @ ent^T  (K=96; rank-1 si term via col 64) ----
        f32x4 en = zero4;
        #pragma unroll
        for (int ks = 0; ks < 3; ++ks) {
            short8 af  = *(const short8*)&sTMP[wv][swz(l15, ks * 32 + kb, 96)];
            short8 bfv = *(const short8*)&sENT[wv][swz(l15, ks * 32 + kb, 96)];
            en = MFMA(af, bfv, en);
        }
        // softmax over i (rows); col j = l15 fixed; i = lg*4+reg
        float mx = fmaxf(fmaxf(en[0], en[1]), fmaxf(en[2], en[3]));
        mx = fmaxf(mx, __shfl_xor(mx, 16));
        mx = fmaxf(mx, __shfl_xor(mx, 32));
        float p0 = __expf(en[0] - mx), p1 = __expf(en[1] - mx);
        float p2 = __expf(en[2] - mx), p3 = __expf(en[3] - mx);
        float s = p0 + p1 + p2 + p3;
        s += __shfl_xor(s, 16);
        s += __shfl_xor(s, 32);
        float inv = 1.f / s;
        float r0 = p0 * inv, r1 = p1 * inv, r2 = p2 * inv, r3 = p3 * inv;
        // rowsum over j (across l15)
        r0 += __shfl_xor(r0, 1); r0 += __shfl_xor(r0, 2); r0 += __shfl_xor(r0, 4); r0 += __shfl_xor(r0, 8);
        r1 += __shfl_xor(r1, 1); r1 += __shfl_xor(r1, 2); r1 += __shfl_xor(r1, 4); r1 += __shfl_xor(r1, 8);
        r2 += __shfl_xor(r2, 1); r2 += __shfl_xor(r2, 2); r2 += __shfl_xor(r2, 4); r2 += __shfl_xor(r2, 8);
        r3 += __shfl_xor(r3, 1); r3 += __shfl_xor(r3, 2); r3 += __shfl_xor(r3, 4); r3 += __shfl_xor(r3, 8);
        if (l15 == 0) {
            sRS[wv][lg * 4 + 0] = r0;
            sRS[wv][lg * 4 + 1] = r1;
            sRS[wv][lg * 4 + 2] = r2;
            sRS[wv][lg * 4 + 3] = r3;
        }
        // attn_out[e] = (1/16) sum_n rs[n] * ent[n][e]   (lane = e)
        float ao = 0.f;
        #pragma unroll
        for (int n = 0; n < 16; ++n)
            ao += sRS[wv][n] * bf2f(sENT[wv][swz(n, lane, 96)]);
        sAO[swz(tl, lane, 64)] = bfr(ao * 0.0625f);
        // mean mu
        float mmv = 0.f;
        #pragma unroll
        for (int a = 0; a < 8; ++a) mmv += mu[t * 512 + a * 64 + lane];
        sMM[swz(tl, lane, 64)] = bfr(mmv * 0.125f);
    }
    __syncthreads();

    // ================= phase 3: z/b1/rv block GEMM (M=16 tokens) =================
    {
        f32x4 zb0 = zero4, zb1 = zero4;
        #pragma unroll
        for (int ks = 0; ks < 4; ++ks) {
            const unsigned short* Ab = (ks < 2) ? sAO : sMM;
            short8 af = *(const short8*)&Ab[swz(l15, (ks & 1) * 32 + kb, 64)];
            short8 b0 = *(const short8*)&ZBRT[((2 * wv + 0) * 16 + l15) * 128 + ks * 32 + kb];
            short8 b1 = *(const short8*)&ZBRT[((2 * wv + 1) * 16 + l15) * 128 + ks * 32 + kb];
            zb0 = MFMA(af, b0, zb0);
            zb1 = MFMA(af, b1, zb1);
        }
        if (wv < 2) {                       // cols 0..63: z = relu(...)
            int c0 = (2 * wv + 0) * 16 + l15, c1 = (2 * wv + 1) * 16 + l15;
            float bz0 = BHF[c0], bz1 = BHF[c1];
            #pragma unroll
            for (int reg = 0; reg < 4; ++reg) {
                int tok = lg * 4 + reg;
                sZ[swz(tok, c0, 64)] = bfr(fmaxf(zb0[reg] + bz0, 0.f));
                sZ[swz(tok, c1, 64)] = bfr(fmaxf(zb1[reg] + bz1, 0.f));
            }
        } else if (wv == 2) {               // cols 64..95: b1
            int m0 = l15, m1 = 16 + l15;
            float bb0 = BB1[m0], bb1 = BB1[m1];
            #pragma unroll
            for (int reg = 0; reg < 4; ++reg) {
                int tok = lg * 4 + reg;
                sB1[tok * 32 + m0] = zb0[reg] + bb0;
                sB1[tok * 32 + m1] = zb1[reg] + bb1;
            }
        } else {                            // cols 96..127: rv -> v scalar
            int m0 = l15, m1 = 16 + l15;
            float bv0 = BV[m0], bv1 = BV[m1];
            float vw0 = v_w2[m0], vw1 = v_w2[m1];
            #pragma unroll
            for (int reg = 0; reg < 4; ++reg) {
                float vp = fmaxf(zb0[reg] + bv0, 0.f) * vw0
                         + fmaxf(zb1[reg] + bv1, 0.f) * vw1;
                vp += __shfl_xor(vp, 1); vp += __shfl_xor(vp, 2);
                vp += __shfl_xor(vp, 4); vp += __shfl_xor(vp, 8);
                if (l15 == 0) sV[lg * 4 + reg] = vp;
            }
        }
    }
    __syncthreads();

    // ================= phase 5: wf (wave0) + per-pair h1/w1 =================
    if (wv == 0) {
        f32x4 w0 = zero4, w1 = zero4;
        #pragma unroll
        for (int ks = 0; ks < 2; ++ks) {
            short8 af = *(const short8*)&sZ[swz(l15, ks * 32 + kb, 64)];
            short8 b0 = *(const short8*)&WFT[(l15) * 64 + ks * 32 + kb];
            short8 b1 = *(const short8*)&WFT[(16 + l15) * 64 + ks * 32 + kb];
            w0 = MFMA(af, b0, w0);
            w1 = MFMA(af, b1, w1);
        }
        float hb0 = hwf_b2[l15], hb1 = hwf_b2[16 + l15];
        #pragma unroll
        for (int reg = 0; reg < 4; ++reg) {
            int tok = lg * 4 + reg;
            sWF[tok * 32 + l15]      = fabsf(w0[reg] + hb0);
            sWF[tok * 32 + 16 + l15] = fabsf(w1[reg] + hb1);
        }
    }

    float hidA[2], hidB[2];
    #pragma unroll
    for (int p = 0; p < 2; ++p) {
        const int tlA = wv * 4 + 2 * p;
        const size_t tA = (size_t)(tok0 + tlA);

        // ---- h1 = relu([states_ally | mu | ao] @ H1T + BH1), 2 tokens ----
        f32x4 h[4] = {zero4, zero4, zero4, zero4};
        #pragma unroll
        for (int ks = 0; ks < 6; ++ks) {
            short8 af;
            if (ks < 2)
                af = cvt8(states + (tA + (l15 >> 3)) * 1024 + (l15 & 7) * 64 + ks * 32 + kb);
            else if (ks < 4)
                af = cvt8(mu + (tA + (l15 >> 3)) * 512 + (l15 & 7) * 64 + (ks - 2) * 32 + kb);
            else
                af = *(const short8*)&sAO[swz(tlA + (l15 >> 3), (ks - 4) * 32 + kb, 64)];
            #pragma unroll
            for (int nt = 0; nt < 4; ++nt) {
                short8 bfv = *(const short8*)&H1T[(nt * 16 + l15) * 192 + ks * 32 + kb];
                h[nt] = MFMA(af, bfv, h[nt]);
            }
        }
        #pragma unroll
        for (int nt = 0; nt < 4; ++nt) {
            int col = nt * 16 + l15;
            float bh = BH1[col];
            #pragma unroll
            for (int reg = 0; reg < 4; ++reg)
                sTMP[wv][swz(lg * 4 + reg, col, 64)] = bfr(fmaxf(h[nt][reg] + bh, 0.f));
        }

        // ---- w1 = |h1 @ W2T + hw1_b2|; hidden-pre = sum_a qs*|w1| ----
        f32x4 wa = zero4, wb = zero4;
        #pragma unroll
        for (int ks = 0; ks < 2; ++ks) {
            short8 af = *(const short8*)&sTMP[wv][swz(l15, ks * 32 + kb, 64)];
            short8 b0 = *(const short8*)&W2T[(l15) * 64 + ks * 32 + kb];
            short8 b1 = *(const short8*)&W2T[(16 + l15) * 64 + ks * 32 + kb];
            wa = MFMA(af, b0, wa);
            wb = MFMA(af, b1, wb);
        }
        float b20 = hw1_b2[l15], b21 = hw1_b2[16 + l15];
        float hp0 = 0.f, hp1 = 0.f;
        #pragma unroll
        for (int reg = 0; reg < 4; ++reg) {
            int row = lg * 4 + reg;
            float qsv = agent_qs[(tA + (row >> 3)) * 8 + (row & 7)];
            hp0 += qsv * fabsf(wa[reg] + b20);
            hp1 += qsv * fabsf(wb[reg] + b21);
        }
        hp0 += __shfl_xor(hp0, 16);        // sum over 8 agents (group pairs)
        hp1 += __shfl_xor(hp1, 16);
        int tl = tlA + (lg >> 1);
        float e0 = hp0 + sB1[tl * 32 + l15];
        float e1 = hp1 + sB1[tl * 32 + 16 + l15];
        hidA[p] = e0 > 0.f ? e0 : (__expf(e0) - 1.f);   // elu
        hidB[p] = e1 > 0.f ? e1 : (__expf(e1) - 1.f);
    }
    __syncthreads();

    // ================= final: q_tot = hidden.wf + v + v_b2 =================
    float vb2 = v_b2[0];
    #pragma unroll
    for (int p = 0; p < 2; ++p) {
        int tl = wv * 4 + 2 * p + (lg >> 1);
        float q = hidA[p] * sWF[tl * 32 + l15] + hidB[p] * sWF[tl * 32 + 16 + l15];
        q += __shfl_xor(q, 1); q += __shfl_xor(q, 2);
        q += __shfl_xor(q, 4); q += __shfl_xor(q, 8);
        if (l15 == 0 && (lg & 1) == 0)
            out[tok0 + tl] = q + sV[tl] + vb2;
    }
}

// ---------------------------------------------------------------------------
extern "C" void kernel_launch(void* const* d_in, const int* in_sizes, int n_in,
                              void* d_out, int out_size, void* d_ws, size_t ws_size,
                              hipStream_t stream)
{
    const float* agent_qs = (const float*)d_in[0];
    const float* states   = (const float*)d_in[1];
    const float* mu       = (const float*)d_in[2];
    const float* ally_w   = (const float*)d_in[3];
    const float* ally_b   = (const float*)d_in[4];
    const float* enemy_w  = (const float*)d_in[5];
    const float* enemy_b  = (const float*)d_in[6];
    const float* q_w      = (const float*)d_in[7];
    // d_in[8] = q_b: cancels in softmax over query axis
    const float* k_w      = (const float*)d_in[9];
    const float* k_b      = (const float*)d_in[10];
    const float* hw1_w1   = (const float*)d_in[11];
    const float* hw1_b1   = (const float*)d_in[12];
    const float* hw1_w2   = (const float*)d_in[13];
    const float* hw1_b2   = (const float*)d_in[14];
    const float* hwf_w1   = (const float*)d_in[15];
    const float* hwf_b1   = (const float*)d_in[16];
    const float* hwf_w2   = (const float*)d_in[17];
    const float* hwf_b2   = (const float*)d_in[18];
    const float* hb1_w    = (const float*)d_in[19];
    const float* hb1_b    = (const float*)d_in[20];
    const float* v_w1     = (const float*)d_in[21];
    const float* v_b1     = (const float*)d_in[22];
    const float* v_w2     = (const float*)d_in[23];
    const float* v_b2     = (const float*)d_in[24];
    const float* tre_w    = (const float*)d_in[25];
    const float* tre_b    = (const float*)d_in[26];

    unsigned short* wsb = (unsigned short*)d_ws;
    float* wsf = (float*)((char*)d_ws + (size_t)E_BF16_TOTAL * 2);
    float* out = (float*)d_out;

    hipLaunchKernelGGL(qmix_setup, dim3(181), dim3(256), 0, stream,
                       ally_w, enemy_w, q_w, k_w, k_b,
                       hw1_w1, hw1_b1, hw1_w2,
                       hwf_w1, hwf_b1, hwf_w2,
                       hb1_w, hb1_b, v_w1, v_b1, tre_w, tre_b,
                       wsb, wsf);

    hipLaunchKernelGGL(qmix_mfma, dim3(TOKS / 16), dim3(256), 0, stream,
                       agent_qs, states, mu, ally_b, enemy_b,
                       v_w2, v_b2, hw1_b2, hwf_b2,
                       wsb, wsf, out);
}